// Round 12
// baseline (177.076 us; speedup 1.0000x reference)
//
#include <hip/hip_runtime.h>

typedef unsigned short u16;
typedef unsigned int   u32;
typedef __attribute__((ext_vector_type(8))) short s16x8;
typedef __attribute__((ext_vector_type(4))) float f32x4;
typedef __attribute__((ext_vector_type(4))) u32   u32x4;

#define DEV static __device__ __forceinline__

static constexpr int B_ = 256, C_ = 64, D_ = 256, H_ = 4096, O_ = 256, E_ = 4;

DEV u16 f2bf(float f) {
  u32 u = __builtin_bit_cast(u32, f);
  u += 0x7fffu + ((u >> 16) & 1u);   // RNE
  return (u16)(u >> 16);
}
DEV float bf2f(u16 u) { return __builtin_bit_cast(float, (u32)u << 16); }

DEV void async16(const u16* g, u16* l) {
  __builtin_amdgcn_global_load_lds(
      (const __attribute__((address_space(1))) void*)g,
      (__attribute__((address_space(3))) void*)l, 16, 0, 0);
}

DEV int xcd_swz(int bid, int nwg) { return (bid & 7) * (nwg >> 3) + (bid >> 3); }

// ---- merged prep: x->bf16 | W1 transpose | W2 transpose | mask | channel sort ----
__global__ void k_prep(const float* __restrict__ x, u16* __restrict__ xb,
                       const float* __restrict__ W1, u16* __restrict__ w1t,
                       const float* __restrict__ W2, u16* __restrict__ w2t,
                       const int* __restrict__ mask, float* __restrict__ maskOut,
                       const int* __restrict__ proj, int* __restrict__ perm) {
  __shared__ float tile[64][65];
  const int bx = blockIdx.x, tid = threadIdx.x;
  if (bx < 2048) {                       // cvt: 8 f32 -> 8 bf16 per thread
    const int i = bx * 256 + tid;
    const f32x4 a = ((const f32x4*)x)[2 * i];
    const f32x4 b = ((const f32x4*)x)[2 * i + 1];
    u32x4 o;
    o[0] = (u32)f2bf(a[0]) | ((u32)f2bf(a[1]) << 16);
    o[1] = (u32)f2bf(a[2]) | ((u32)f2bf(a[3]) << 16);
    o[2] = (u32)f2bf(b[0]) | ((u32)f2bf(b[1]) << 16);
    o[3] = (u32)f2bf(b[2]) | ((u32)f2bf(b[3]) << 16);
    ((u32x4*)xb)[i] = o;
    return;
  }
  if (bx < 4096) {                       // transpose f32 [R][C] -> bf16 [C][R]
    const bool w1 = bx < 3072;
    const int R  = w1 ? D_ : H_;
    const int Cc = w1 ? H_ : O_;
    const float* s0 = w1 ? W1 : W2;
    u16* d0 = w1 ? w1t : w2t;
    int b = bx - (w1 ? 2048 : 3072);
    const int nct = Cc >> 6, nrt = R >> 6;
    const int ct = b % nct; b /= nct;
    const int rt = b % nrt; const int e = b / nrt;
    const float* s = s0 + (size_t)e * R * Cc;
    u16* d = d0 + (size_t)e * R * Cc;
    const int tx = tid & 63, ty = tid >> 6;
    #pragma unroll
    for (int i = 0; i < 64; i += 4)
      tile[i + ty][tx] = s[(size_t)(rt * 64 + i + ty) * Cc + ct * 64 + tx];
    __syncthreads();
    #pragma unroll
    for (int i = 0; i < 64; i += 4) {
      const int cc = i + ty;
      d[(size_t)(ct * 64 + cc) * R + rt * 64 + tx] = f2bf(tile[tx][cc]);
    }
    return;
  }
  if (bx < 4104) {                       // mask passthrough as f32 (8 ints/thread)
    const int i = (bx - 4096) * 256 + tid;
    #pragma unroll
    for (int j = 0; j < 8; ++j) maskOut[i * 8 + j] = (float)mask[i * 8 + j];
    return;
  }
  // counting sort of channels by expert (deterministic)
  if (tid < C_) {
    const int e = proj[tid];
    int rank = 0;
    for (int c2 = 0; c2 < C_; ++c2) {
      const int e2 = proj[c2];
      rank += (e2 < e) || (e2 == e && c2 < tid);
    }
    perm[rank] = tid;
  }
}

// ---------------- GEMM1: h = x*W1 + b1, ATOMIC-FREE per-(c,bt) stats partials ----------
// h layout: TILED [c][nt=32][B][128] -> epilogue is one contiguous 32KB block store.
// 2-buffer gload_lds, vmcnt(0)/step (proven sync scheme, unchanged).
__global__ __launch_bounds__(256, 4)
void k_gemm1(const u16* __restrict__ A, const u16* __restrict__ Bw,
             const int* __restrict__ proj, const int* __restrict__ perm,
             const float* __restrict__ bias,
             u16* __restrict__ outH, float* __restrict__ s1p, float* __restrict__ s2p) {
  constexpr int BM = 128, BN = 128, BK = 32, KT = D_ / BK;   // 8 K-steps
  constexpr int SA = BM * BK / 8, SB = BN * BK / 8;          // 512, 512 16B-slots
  constexpr int BUF = (SA + SB) * 8;                         // 16KB
  __shared__ __align__(16) u16 lds[2 * BUF];                 // 32 KB
  __shared__ float stash[2][4][16][2];                       // wm=1 wave stats (1 KB)
  const int tid = threadIdx.x, l = tid & 63, w = tid >> 6, wm = w >> 1, wn = w & 1;

  int bid = xcd_swz(blockIdx.x, gridDim.x);
  constexpr int NT = H_ / BN, BT = B_ / BM;                  // 32, 2
  const int nt = bid % NT; bid /= NT;
  const int bt = bid % BT; const int ci = bid / BT;
  const int c = perm[ci];
  const int e = proj[c];

  const size_t rsA = (size_t)C_ * D_;
  const u16* Ab = A + (size_t)c * D_ + (size_t)bt * BM * rsA;
  const u16* Bb = Bw + ((size_t)e * H_ + (size_t)nt * BN) * D_;

  f32x4 acc[4][4] = {};

  auto stage = [&](int kt) {           // 4 glds per thread (2 A + 2 B)
    const int k0 = kt * BK;
    u16* dst = lds + (kt & 1) * BUF;
    #pragma unroll
    for (int i = 0; i < 2; ++i) {
      const int s = i * 256 + tid, row = s >> 2, j = (s & 3) ^ ((row >> 1) & 3);
      async16(Ab + (size_t)row * rsA + k0 + j * 8, dst + s * 8);
    }
    #pragma unroll
    for (int i = 0; i < 2; ++i) {
      const int s = i * 256 + tid, col = s >> 2, j = (s & 3) ^ ((col >> 1) & 3);
      async16(Bb + (size_t)col * D_ + k0 + j * 8, dst + SA * 8 + s * 8);
    }
  };

  stage(0);
  asm volatile("s_waitcnt vmcnt(0)" ::: "memory");
  __builtin_amdgcn_s_barrier();

  #pragma unroll
  for (int kt = 0; kt < KT; ++kt) {
    if (kt + 1 < KT) stage(kt + 1);          // prefetch overlaps compute below
    const u16* bufA = lds + (kt & 1) * BUF;
    const u16* bufB = bufA + SA * 8;
    s16x8 av[4], bv[4];
    #pragma unroll
    for (int m = 0; m < 4; ++m) {
      const int r = wm * 64 + m * 16 + (l & 15), p = (l >> 4) ^ ((r >> 1) & 3);
      av[m] = *(const s16x8*)(bufA + (r * 4 + p) * 8);
    }
    #pragma unroll
    for (int n = 0; n < 4; ++n) {
      const int cc = wn * 64 + n * 16 + (l & 15), p = (l >> 4) ^ ((cc >> 1) & 3);
      bv[n] = *(const s16x8*)(bufB + (cc * 4 + p) * 8);
    }
    #pragma unroll
    for (int m = 0; m < 4; ++m)
      #pragma unroll
      for (int n = 0; n < 4; ++n)
        acc[m][n] = __builtin_amdgcn_mfma_f32_16x16x32_bf16(av[m], bv[n], acc[m][n], 0, 0, 0);
    asm volatile("s_waitcnt vmcnt(0) lgkmcnt(0)" ::: "memory");
    __builtin_amdgcn_s_barrier();
  }

  // epilogue: bias + per-wave stats + bf16 pack into LDS (XOR swizzle)
  u16* ldsOut = lds;
  float p1s[4], p2s[4];
  #pragma unroll
  for (int n = 0; n < 4; ++n) {
    const int colL = wn * 64 + n * 16 + (l & 15);
    const int colg = nt * BN + colL;
    const float bval = bias[e * H_ + colg];
    float p1 = 0.f, p2 = 0.f;
    #pragma unroll
    for (int m = 0; m < 4; ++m) {
      const int rbase = wm * 64 + m * 16 + (l >> 4) * 4;
      #pragma unroll
      for (int i = 0; i < 4; ++i) {
        const float v = acc[m][n][i] + bval;
        p1 += v; p2 += v * v;
        const int row = rbase + i;
        const int phys = (colL >> 3) ^ (row & 15);
        ldsOut[row * 128 + phys * 8 + (colL & 7)] = f2bf(v);
      }
    }
    p1 += __shfl_xor(p1, 16); p1 += __shfl_xor(p1, 32);
    p2 += __shfl_xor(p2, 16); p2 += __shfl_xor(p2, 32);
    if (wm == 1 && l < 16) { stash[wn][n][l & 15][0] = p1; stash[wn][n][l & 15][1] = p2; }
    p1s[n] = p1; p2s[n] = p2;
  }
  __syncthreads();
  // cross-wave (wm) combine + race-free store: slot (c*2+bt, colg) owned uniquely
  if (wm == 0 && l < 16) {
    const int rowp = c * 2 + bt;
    #pragma unroll
    for (int n = 0; n < 4; ++n) {
      const int colg = nt * BN + wn * 64 + n * 16 + (l & 15);
      s1p[(size_t)rowp * H_ + colg] = p1s[n] + stash[wn][n][l & 15][0];
      s2p[(size_t)rowp * H_ + colg] = p2s[n] + stash[wn][n][l & 15][1];
    }
  }
  // h store: tiled [c][nt][B][128] -> one contiguous 32 KB chunk (4 KB per pass)
  u16* outB = outH + (((size_t)c * NT + nt) * B_ + (size_t)bt * BM) * 128;
  #pragma unroll
  for (int pass = 0; pass < 8; ++pass) {
    const int row = pass * 16 + (tid >> 4), sl = tid & 15;
    const u32x4 v = *(const u32x4*)(ldsOut + row * 128 + ((sl ^ (row & 15)) * 8));
    *(u32x4*)(outB + (size_t)row * 128 + sl * 8) = v;
  }
}

// ---------------- BN finalize: segment-sum partials -> bf16 scale/shift ----------------
__global__ void k_finalize(const float* __restrict__ s1p, const float* __restrict__ s2p,
                           const int* __restrict__ proj, const float* __restrict__ gamma,
                           const float* __restrict__ beta,
                           u16* __restrict__ sclB, u16* __restrict__ shfB) {
  const int i = blockIdx.x * 256 + threadIdx.x;   // over E*H
  const int e = i >> 12;                          // H = 4096
  const int hcol = i & 4095;
  int cn = 0;
  float q1 = 0.f, q2 = 0.f;
  for (int c = 0; c < C_; ++c) {
    if (proj[c] == e) {
      ++cn;
      q1 += s1p[(size_t)(c * 2) * H_ + hcol] + s1p[(size_t)(c * 2 + 1) * H_ + hcol];
      q2 += s2p[(size_t)(c * 2) * H_ + hcol] + s2p[(size_t)(c * 2 + 1) * H_ + hcol];
    }
  }
  const float cnt = fmaxf((float)cn * (float)B_, 1.f);
  const float mean = q1 / cnt;
  const float var = q2 / cnt - mean * mean;       // biased (train-mode BN)
  const float sc = rsqrtf(var + 1e-5f) * gamma[i];
  sclB[i] = f2bf(sc);
  shfB[i] = f2bf(beta[i] - mean * sc);
}

// ---------------- GEMM2: out = relu(scale*h+shift)*W2 + b2 ----------------
// BM=32, BN=256, KS=1 (no split-K, no combine). Fully reg-staged, lgkm-only sync
// (proven). h read from tiled [c][nt][B][128]. 52 KB LDS -> 3 blocks/CU.
__global__ __launch_bounds__(256, 3)
void k_gemm2(const u16* __restrict__ A, const u16* __restrict__ Bw,
             const int* __restrict__ proj, const int* __restrict__ perm,
             const float* __restrict__ b2,
             const u16* __restrict__ scB, const u16* __restrict__ shB,
             float* __restrict__ outF) {
  constexpr int BM = 32, BN = 256, BK = 32, KT = H_ / BK;    // 128 K-steps
  constexpr int SA = BM * BK / 8, SB = BN * BK / 8;          // 128, 1024 16B-slots
  constexpr int BUF = (SA + SB) * 8;                         // 18 KB (u16 units: 9216)
  __shared__ __align__(16) u16 lds[2 * BUF + 2 * H_];        // 36 + 16 KB
  u16* stS = lds + 2 * BUF;          // scale[H]
  u16* stT = stS + H_;               // shift[H]
  const int tid = threadIdx.x, l = tid & 63, w = tid >> 6;   // w = N-wave (0..3)

  int bid = xcd_swz(blockIdx.x, gridDim.x);
  const int bt = bid & 7; const int ci = bid >> 3;           // B_/BM = 8
  const int c = perm[ci];
  const int e = proj[c];

  const u16* Ab = A + (size_t)c * 32 * B_ * 128 + (size_t)bt * BM * 128;  // tiled base
  const u16* Bb = Bw + (size_t)e * O_ * H_;
  const u16* scE = scB + e * H_;
  const u16* shE = shB + e * H_;

  f32x4 acc[2][4] = {};
  s16x8 h0, h1, b0r[4], b1r[4];        // ping-pong reg sets; data k lives in set k&1

  auto Aissue = [&](int kt, s16x8& hs) {
    if (tid < 128) {
      const int k0 = kt * BK;
      const int row = tid >> 2, j = (tid & 3) ^ ((row >> 1) & 3);
      const int k = k0 + j * 8;
      hs = *(const s16x8*)(Ab + (size_t)(k >> 7) * (B_ * 128) + row * 128 + (k & 127));
    }
  };
  auto Bissue = [&](int kt, s16x8 (&bs)[4]) {
    const int k0 = kt * BK;
    #pragma unroll
    for (int i = 0; i < 4; ++i) {
      const int s = i * 256 + tid, col = s >> 2, j = (s & 3) ^ ((col >> 1) & 3);
      bs[i] = *(const s16x8*)(Bb + (size_t)col * H_ + k0 + j * 8);
    }
  };
  auto Awrite = [&](int kt, s16x8& hs) {   // BN apply + ReLU + bf16 pack -> LDS
    if (tid < 128) {
      u16* dst = lds + (kt & 1) * BUF;
      const int k0 = kt * BK;
      const int row = tid >> 2, j = (tid & 3) ^ ((row >> 1) & 3);
      const s16x8 sv = *(const s16x8*)(stS + k0 + j * 8);
      const s16x8 tv = *(const s16x8*)(stT + k0 + j * 8);
      u32x4 o;
      #pragma unroll
      for (int jj = 0; jj < 4; ++jj) {
        const float v0 = fmaxf(bf2f((u16)hs[2 * jj]) * bf2f((u16)sv[2 * jj]) + bf2f((u16)tv[2 * jj]), 0.f);
        const float v1 = fmaxf(bf2f((u16)hs[2 * jj + 1]) * bf2f((u16)sv[2 * jj + 1]) + bf2f((u16)tv[2 * jj + 1]), 0.f);
        o[jj] = (u32)f2bf(v0) | ((u32)f2bf(v1) << 16);
      }
      *(u32x4*)(dst + tid * 8) = o;
    }
  };
  auto Bwrite = [&](int kt, s16x8 (&bs)[4]) {   // raw pass-through -> LDS
    u16* dst = lds + (kt & 1) * BUF + SA * 8;
    #pragma unroll
    for (int i = 0; i < 4; ++i) {
      const int s = i * 256 + tid;
      *(u32x4*)(dst + s * 8) = __builtin_bit_cast(u32x4, bs[i]);
    }
  };
  auto Compute = [&](int kt) {
    const u16* bufA = lds + (kt & 1) * BUF;
    const u16* bufB = bufA + SA * 8;
    s16x8 av[2], bv[4];
    #pragma unroll
    for (int m = 0; m < 2; ++m) {
      const int r = m * 16 + (l & 15), p = (l >> 4) ^ ((r >> 1) & 3);
      av[m] = *(const s16x8*)(bufA + (r * 4 + p) * 8);   // broadcast across waves
    }
    #pragma unroll
    for (int n = 0; n < 4; ++n) {
      const int cc = w * 64 + n * 16 + (l & 15), p = (l >> 4) ^ ((cc >> 1) & 3);
      bv[n] = *(const s16x8*)(bufB + (cc * 4 + p) * 8);
    }
    #pragma unroll
    for (int m = 0; m < 2; ++m)
      #pragma unroll
      for (int n = 0; n < 4; ++n)
        acc[m][n] = __builtin_amdgcn_mfma_f32_16x16x32_bf16(av[m], bv[n], acc[m][n], 0, 0, 0);
  };

  // prologue: st DMA + first two steps' reg loads; drain own VMEM, then BARRIER
  // (cross-wave DMA visibility), then first write.
  for (int q = tid; q < H_ / 4; q += 256) {
    if (q < H_ / 8) async16(scE + q * 8, stS + q * 8);
    else            async16(shE + (q - H_ / 8) * 8, stT + (q - H_ / 8) * 8);
  }
  Aissue(0, h0); Bissue(0, b0r);
  Aissue(1, h1); Bissue(1, b1r);
  asm volatile("s_waitcnt vmcnt(0)" ::: "memory");
  __builtin_amdgcn_s_barrier();              // st visible to ALL waves
  Awrite(0, h0); Bwrite(0, b0r);
  asm volatile("s_waitcnt lgkmcnt(0)" ::: "memory");
  __builtin_amdgcn_s_barrier();

  // steady: {issue(kt+2); compute(kt); write(kt+1); lgkm0; barrier} x2
  #pragma unroll 1
  for (int kt = 0; kt + 3 < KT; kt += 2) {
    Aissue(kt + 2, h0); Bissue(kt + 2, b0r);
    Compute(kt);
    Awrite(kt + 1, h1); Bwrite(kt + 1, b1r);
    asm volatile("s_waitcnt lgkmcnt(0)" ::: "memory");
    __builtin_amdgcn_s_barrier();
    Aissue(kt + 3, h1); Bissue(kt + 3, b1r);
    Compute(kt + 1);
    Awrite(kt + 2, h0); Bwrite(kt + 2, b0r);
    asm volatile("s_waitcnt lgkmcnt(0)" ::: "memory");
    __builtin_amdgcn_s_barrier();
  }

  // tail: steps KT-2, KT-1
  Compute(KT - 2);
  Awrite(KT - 1, h1); Bwrite(KT - 1, b1r);
  asm volatile("s_waitcnt lgkmcnt(0)" ::: "memory");
  __builtin_amdgcn_s_barrier();
  Compute(KT - 1);

  // epilogue: direct out + b2 (no partial, no combine)
  #pragma unroll
  for (int n = 0; n < 4; ++n) {
    const int colg = w * 64 + n * 16 + (l & 15);
    const float bval = b2[e * O_ + colg];
    #pragma unroll
    for (int m = 0; m < 2; ++m) {
      #pragma unroll
      for (int i = 0; i < 4; ++i) {
        const int rg = bt * BM + m * 16 + (l >> 4) * 4 + i;
        outF[((size_t)rg * C_ + c) * O_ + colg] = acc[m][n][i] + bval;
      }
    }
  }
}

extern "C" void kernel_launch(void* const* d_in, const int* in_sizes, int n_in,
                              void* d_out, int out_size, void* d_ws, size_t ws_size,
                              hipStream_t stream) {
  const float* x     = (const float*)d_in[0];
  const int*   mask  = (const int*)d_in[1];
  const int*   proj  = (const int*)d_in[2];
  const float* W1    = (const float*)d_in[3];
  const float* b1    = (const float*)d_in[4];
  const float* gamma = (const float*)d_in[5];
  const float* beta  = (const float*)d_in[6];
  const float* W2    = (const float*)d_in[7];
  const float* b2    = (const float*)d_in[8];
  float* out = (float*)d_out;

  char* ws = (char*)d_ws;
  size_t off = 0;
  u16* hbuf = (u16*)(ws + off); off += (size_t)B_ * C_ * H_ * 2;   // 128 MB, tiled [c][32][B][128]
  u16* xb   = (u16*)(ws + off); off += (size_t)B_ * C_ * D_ * 2;   // 8 MB
  u16* w1t  = (u16*)(ws + off); off += (size_t)E_ * D_ * H_ * 2;   // 8 MB  [E][H][D]
  u16* w2t  = (u16*)(ws + off); off += (size_t)E_ * H_ * O_ * 2;   // 8 MB  [E][O][H]
  float* s1p = (float*)(ws + off); off += (size_t)2 * C_ * H_ * 4; // 2 MB [c*2+bt][H]
  float* s2p = (float*)(ws + off); off += (size_t)2 * C_ * H_ * 4; // 2 MB
  u16* sclB = (u16*)(ws + off); off += (size_t)E_ * H_ * 2;
  u16* shfB = (u16*)(ws + off); off += (size_t)E_ * H_ * 2;
  int* perm = (int*)(ws + off); off += 256;

  // no memset needed: s1p/s2p fully overwritten by gemm1 (every (c,bt,colg) once)

  k_prep<<<4105, 256, 0, stream>>>(x, xb, W1, w1t, W2, w2t, mask,
                                   out + (size_t)B_ * C_ * O_, proj, perm);

  k_gemm1<<<C_ * 2 * 32, 256, 0, stream>>>(xb, w1t, proj, perm, b1, hbuf, s1p, s2p);

  k_finalize<<<E_ * H_ / 256, 256, 0, stream>>>(s1p, s2p, proj, gamma, beta, sclB, shfB);

  // grid = C * (B/32) = 512 blocks, no split-K
  k_gemm2<<<512, 256, 0, stream>>>(hbuf, w2t, proj, perm, b2, sclB, shfB, out);
}

// Round 13
// 151.197 us; speedup vs baseline: 1.1712x; 1.1712x over previous
//
#include <hip/hip_runtime.h>

typedef unsigned short u16;
typedef unsigned int   u32;
typedef __attribute__((ext_vector_type(8))) short s16x8;
typedef __attribute__((ext_vector_type(4))) float f32x4;
typedef __attribute__((ext_vector_type(4))) u32   u32x4;

#define DEV static __device__ __forceinline__

static constexpr int B_ = 256, C_ = 64, D_ = 256, H_ = 4096, O_ = 256, E_ = 4;

DEV u16 f2bf(float f) {
  u32 u = __builtin_bit_cast(u32, f);
  u += 0x7fffu + ((u >> 16) & 1u);   // RNE
  return (u16)(u >> 16);
}
DEV float bf2f(u16 u) { return __builtin_bit_cast(float, (u32)u << 16); }

DEV void async16(const u16* g, u16* l) {
  __builtin_amdgcn_global_load_lds(
      (const __attribute__((address_space(1))) void*)g,
      (__attribute__((address_space(3))) void*)l, 16, 0, 0);
}

DEV int xcd_swz(int bid, int nwg) { return (bid & 7) * (nwg >> 3) + (bid >> 3); }

// ---- merged prep: x->bf16 | W1 transpose | W2 transpose | mask | channel sort ----
__global__ void k_prep(const float* __restrict__ x, u16* __restrict__ xb,
                       const float* __restrict__ W1, u16* __restrict__ w1t,
                       const float* __restrict__ W2, u16* __restrict__ w2t,
                       const int* __restrict__ mask, float* __restrict__ maskOut,
                       const int* __restrict__ proj, int* __restrict__ perm) {
  __shared__ float tile[64][65];
  const int bx = blockIdx.x, tid = threadIdx.x;
  if (bx < 2048) {                       // cvt: 8 f32 -> 8 bf16 per thread
    const int i = bx * 256 + tid;
    const f32x4 a = ((const f32x4*)x)[2 * i];
    const f32x4 b = ((const f32x4*)x)[2 * i + 1];
    u32x4 o;
    o[0] = (u32)f2bf(a[0]) | ((u32)f2bf(a[1]) << 16);
    o[1] = (u32)f2bf(a[2]) | ((u32)f2bf(a[3]) << 16);
    o[2] = (u32)f2bf(b[0]) | ((u32)f2bf(b[1]) << 16);
    o[3] = (u32)f2bf(b[2]) | ((u32)f2bf(b[3]) << 16);
    ((u32x4*)xb)[i] = o;
    return;
  }
  if (bx < 4096) {                       // transpose f32 [R][C] -> bf16 [C][R]
    const bool w1 = bx < 3072;
    const int R  = w1 ? D_ : H_;
    const int Cc = w1 ? H_ : O_;
    const float* s0 = w1 ? W1 : W2;
    u16* d0 = w1 ? w1t : w2t;
    int b = bx - (w1 ? 2048 : 3072);
    const int nct = Cc >> 6, nrt = R >> 6;
    const int ct = b % nct; b /= nct;
    const int rt = b % nrt; const int e = b / nrt;
    const float* s = s0 + (size_t)e * R * Cc;
    u16* d = d0 + (size_t)e * R * Cc;
    const int tx = tid & 63, ty = tid >> 6;
    #pragma unroll
    for (int i = 0; i < 64; i += 4)
      tile[i + ty][tx] = s[(size_t)(rt * 64 + i + ty) * Cc + ct * 64 + tx];
    __syncthreads();
    #pragma unroll
    for (int i = 0; i < 64; i += 4) {
      const int cc = i + ty;
      d[(size_t)(ct * 64 + cc) * R + rt * 64 + tx] = f2bf(tile[tx][cc]);
    }
    return;
  }
  if (bx < 4104) {                       // mask passthrough as f32 (8 ints/thread)
    const int i = (bx - 4096) * 256 + tid;
    #pragma unroll
    for (int j = 0; j < 8; ++j) maskOut[i * 8 + j] = (float)mask[i * 8 + j];
    return;
  }
  // counting sort of channels by expert (deterministic)
  if (tid < C_) {
    const int e = proj[tid];
    int rank = 0;
    for (int c2 = 0; c2 < C_; ++c2) {
      const int e2 = proj[c2];
      rank += (e2 < e) || (e2 == e && c2 < tid);
    }
    perm[rank] = tid;
  }
}

// ---------------- GEMM1: h = x*W1 + b1, atomic-free stats, tiled-h store ----------
// 3-buffer COUNTED vmcnt pipeline (homogeneous gload_lds; per-step
// vmcnt(4)+lgkmcnt(0) closes both the DMA-landing and the pending-ds_read-
// across-barrier hazards). One barrier per step, no full drain.
__global__ __launch_bounds__(256, 3)
void k_gemm1(const u16* __restrict__ A, const u16* __restrict__ Bw,
             const int* __restrict__ proj, const int* __restrict__ perm,
             const float* __restrict__ bias,
             u16* __restrict__ outH, float* __restrict__ s1p, float* __restrict__ s2p) {
  constexpr int BM = 128, BN = 128, BK = 32, KT = D_ / BK;   // 8 K-steps
  constexpr int SA = BM * BK / 8, SB = BN * BK / 8;          // 512, 512 16B-slots
  constexpr int BUF = (SA + SB) * 8;                         // 16KB
  __shared__ __align__(16) u16 lds[3 * BUF];                 // 48 KB
  __shared__ float stash[2][4][16][2];                       // wm=1 wave stats (1 KB)
  const int tid = threadIdx.x, l = tid & 63, w = tid >> 6, wm = w >> 1, wn = w & 1;

  int bid = xcd_swz(blockIdx.x, gridDim.x);
  constexpr int NT = H_ / BN, BT = B_ / BM;                  // 32, 2
  const int nt = bid % NT; bid /= NT;
  const int bt = bid % BT; const int ci = bid / BT;
  const int c = perm[ci];
  const int e = proj[c];

  const size_t rsA = (size_t)C_ * D_;
  const u16* Ab = A + (size_t)c * D_ + (size_t)bt * BM * rsA;
  const u16* Bb = Bw + ((size_t)e * H_ + (size_t)nt * BN) * D_;

  f32x4 acc[4][4] = {};

  auto stage = [&](int kt) {           // 4 glds per thread (2 A + 2 B)
    const int k0 = kt * BK;
    u16* dst = lds + (kt % 3) * BUF;
    #pragma unroll
    for (int i = 0; i < 2; ++i) {
      const int s = i * 256 + tid, row = s >> 2, j = (s & 3) ^ ((row >> 1) & 3);
      async16(Ab + (size_t)row * rsA + k0 + j * 8, dst + s * 8);
    }
    #pragma unroll
    for (int i = 0; i < 2; ++i) {
      const int s = i * 256 + tid, col = s >> 2, j = (s & 3) ^ ((col >> 1) & 3);
      async16(Bb + (size_t)col * D_ + k0 + j * 8, dst + SA * 8 + s * 8);
    }
  };

  stage(0);
  asm volatile("" ::: "memory");       // stage(0) ops strictly older than stage(1)'s
  stage(1);
  asm volatile("s_waitcnt vmcnt(4)" ::: "memory");   // stage(0) landed
  __builtin_amdgcn_s_barrier();

  #pragma unroll
  for (int kt = 0; kt < KT; ++kt) {
    if (kt + 2 < KT) stage(kt + 2);          // 2-ahead prefetch
    const u16* bufA = lds + (kt % 3) * BUF;
    const u16* bufB = bufA + SA * 8;
    s16x8 av[4], bv[4];
    #pragma unroll
    for (int m = 0; m < 4; ++m) {
      const int r = wm * 64 + m * 16 + (l & 15), p = (l >> 4) ^ ((r >> 1) & 3);
      av[m] = *(const s16x8*)(bufA + (r * 4 + p) * 8);
    }
    #pragma unroll
    for (int n = 0; n < 4; ++n) {
      const int cc = wn * 64 + n * 16 + (l & 15), p = (l >> 4) ^ ((cc >> 1) & 3);
      bv[n] = *(const s16x8*)(bufB + (cc * 4 + p) * 8);
    }
    #pragma unroll
    for (int m = 0; m < 4; ++m)
      #pragma unroll
      for (int n = 0; n < 4; ++n)
        acc[m][n] = __builtin_amdgcn_mfma_f32_16x16x32_bf16(av[m], bv[n], acc[m][n], 0, 0, 0);
    // counted wait: stage(kt+1) landed (4 of stage(kt+2) still in flight);
    // lgkmcnt(0): this wave's ds_reads of buf[kt%3] complete before ANY wave
    // can cross the barrier and issue the DMA that later overwrites it.
    if (kt + 2 < KT)      asm volatile("s_waitcnt vmcnt(4) lgkmcnt(0)" ::: "memory");
    else if (kt + 1 < KT) asm volatile("s_waitcnt vmcnt(0) lgkmcnt(0)" ::: "memory");
    if (kt + 1 < KT) __builtin_amdgcn_s_barrier();
  }
  __syncthreads();                      // all compute done before ldsOut reuse

  // epilogue: bias + per-wave stats + bf16 pack into LDS (XOR swizzle)
  u16* ldsOut = lds;
  float p1s[4], p2s[4];
  #pragma unroll
  for (int n = 0; n < 4; ++n) {
    const int colL = wn * 64 + n * 16 + (l & 15);
    const int colg = nt * BN + colL;
    const float bval = bias[e * H_ + colg];
    float p1 = 0.f, p2 = 0.f;
    #pragma unroll
    for (int m = 0; m < 4; ++m) {
      const int rbase = wm * 64 + m * 16 + (l >> 4) * 4;
      #pragma unroll
      for (int i = 0; i < 4; ++i) {
        const float v = acc[m][n][i] + bval;
        p1 += v; p2 += v * v;
        const int row = rbase + i;
        const int phys = (colL >> 3) ^ (row & 15);
        ldsOut[row * 128 + phys * 8 + (colL & 7)] = f2bf(v);
      }
    }
    p1 += __shfl_xor(p1, 16); p1 += __shfl_xor(p1, 32);
    p2 += __shfl_xor(p2, 16); p2 += __shfl_xor(p2, 32);
    if (wm == 1 && l < 16) { stash[wn][n][l & 15][0] = p1; stash[wn][n][l & 15][1] = p2; }
    p1s[n] = p1; p2s[n] = p2;
  }
  __syncthreads();
  if (wm == 0 && l < 16) {
    const int rowp = c * 2 + bt;
    #pragma unroll
    for (int n = 0; n < 4; ++n) {
      const int colg = nt * BN + wn * 64 + n * 16 + (l & 15);
      s1p[(size_t)rowp * H_ + colg] = p1s[n] + stash[wn][n][l & 15][0];
      s2p[(size_t)rowp * H_ + colg] = p2s[n] + stash[wn][n][l & 15][1];
    }
  }
  // h store: tiled [c][nt][B][128] -> one contiguous 32 KB chunk
  u16* outB = outH + (((size_t)c * NT + nt) * B_ + (size_t)bt * BM) * 128;
  #pragma unroll
  for (int pass = 0; pass < 8; ++pass) {
    const int row = pass * 16 + (tid >> 4), sl = tid & 15;
    const u32x4 v = *(const u32x4*)(ldsOut + row * 128 + ((sl ^ (row & 15)) * 8));
    *(u32x4*)(outB + (size_t)row * 128 + sl * 8) = v;
  }
}

// ---------------- BN finalize: segment-sum partials -> bf16 scale/shift ----------------
__global__ void k_finalize(const float* __restrict__ s1p, const float* __restrict__ s2p,
                           const int* __restrict__ proj, const float* __restrict__ gamma,
                           const float* __restrict__ beta,
                           u16* __restrict__ sclB, u16* __restrict__ shfB) {
  const int i = blockIdx.x * 256 + threadIdx.x;   // over E*H
  const int e = i >> 12;                          // H = 4096
  const int hcol = i & 4095;
  int cn = 0;
  float q1 = 0.f, q2 = 0.f;
  for (int c = 0; c < C_; ++c) {
    if (proj[c] == e) {
      ++cn;
      q1 += s1p[(size_t)(c * 2) * H_ + hcol] + s1p[(size_t)(c * 2 + 1) * H_ + hcol];
      q2 += s2p[(size_t)(c * 2) * H_ + hcol] + s2p[(size_t)(c * 2 + 1) * H_ + hcol];
    }
  }
  const float cnt = fmaxf((float)cn * (float)B_, 1.f);
  const float mean = q1 / cnt;
  const float var = q2 / cnt - mean * mean;       // biased (train-mode BN)
  const float sc = rsqrtf(var + 1e-5f) * gamma[i];
  sclB[i] = f2bf(sc);
  shfB[i] = f2bf(beta[i] - mean * sc);
}

// ---------------- GEMM2: out = relu(scale*h+shift)*W2 + b2, split-K=2 ----------------
// ROUND-9 geometry (proven ~56us): BM=64, BN=256, KS=2, reg-staged, lgkm-only
// full-drain sync. Only change: h read from tiled [c][nt][B][128] layout.
__global__ __launch_bounds__(256, 2)
void k_gemm2(const u16* __restrict__ A, const u16* __restrict__ Bw,
             const int* __restrict__ proj, const int* __restrict__ perm,
             const float* __restrict__ b2,
             const u16* __restrict__ scB, const u16* __restrict__ shB,
             float* __restrict__ outF, float* __restrict__ partial) {
  constexpr int KS = 2;
  constexpr int BM = 64, BN = 256, BK = 32, KH = H_ / KS, KT = KH / BK;  // 64 steps
  constexpr int SA = BM * BK / 8, SB = BN * BK / 8;          // 256, 1024 16B-slots
  constexpr int BUF = (SA + SB) * 8;                         // 20 KB
  __shared__ __align__(16) u16 lds[2 * BUF + 2 * KH];        // 40 + 8 KB
  u16* stS = lds + 2 * BUF;          // scale[KH]
  u16* stT = stS + KH;               // shift[KH]
  const int tid = threadIdx.x, l = tid & 63, w = tid >> 6;   // w = N-wave (0..3)

  int bid = xcd_swz(blockIdx.x, gridDim.x);
  const int ks = bid & 1; bid >>= 1;
  const int bt = bid & 3; const int ci = bid >> 2;           // B_/BM = 4
  const int c = perm[ci];
  const int e = proj[c];

  // tiled h: addr = Ab + (kglob>>7)*(B_*128) + row*128 + (kglob&127)
  const u16* Ab = A + ((size_t)c * 32 * B_ + (size_t)bt * BM) * 128;
  const u16* Bb = Bw + (size_t)e * O_ * H_ + (size_t)ks * KH;   // BN=256 = full O
  const u16* scE = scB + e * H_ + ks * KH;
  const u16* shE = shB + e * H_ + ks * KH;

  f32x4 acc[4][4] = {};
  s16x8 h0[1], h1[1], b0r[4], b1r[4];  // ping-pong reg sets; data k lives in set k&1

  auto Aissue = [&](int kt, s16x8 (&hs)[1]) {
    const int row = tid >> 2, j = (tid & 3) ^ ((row >> 1) & 3);
    const int kg = ks * KH + kt * BK + j * 8;
    hs[0] = *(const s16x8*)(Ab + (size_t)(kg >> 7) * (B_ * 128) + row * 128 + (kg & 127));
  };
  auto Bissue = [&](int kt, s16x8 (&bs)[4]) {
    const int k0 = kt * BK;
    #pragma unroll
    for (int i = 0; i < 4; ++i) {
      const int s = i * 256 + tid, col = s >> 2, j = (s & 3) ^ ((col >> 1) & 3);
      bs[i] = *(const s16x8*)(Bb + (size_t)col * H_ + k0 + j * 8);
    }
  };
  auto Awrite = [&](int kt, s16x8 (&hs)[1]) {   // BN apply + ReLU + bf16 pack -> LDS
    u16* dst = lds + (kt & 1) * BUF;
    const int k0 = kt * BK;
    const int row = tid >> 2, j = (tid & 3) ^ ((row >> 1) & 3);
    const s16x8 sv = *(const s16x8*)(stS + k0 + j * 8);
    const s16x8 tv = *(const s16x8*)(stT + k0 + j * 8);
    u32x4 o;
    #pragma unroll
    for (int jj = 0; jj < 4; ++jj) {
      const float v0 = fmaxf(bf2f((u16)hs[0][2 * jj]) * bf2f((u16)sv[2 * jj]) + bf2f((u16)tv[2 * jj]), 0.f);
      const float v1 = fmaxf(bf2f((u16)hs[0][2 * jj + 1]) * bf2f((u16)sv[2 * jj + 1]) + bf2f((u16)tv[2 * jj + 1]), 0.f);
      o[jj] = (u32)f2bf(v0) | ((u32)f2bf(v1) << 16);
    }
    *(u32x4*)(dst + tid * 8) = o;
  };
  auto Bwrite = [&](int kt, s16x8 (&bs)[4]) {   // raw pass-through -> LDS
    u16* dst = lds + (kt & 1) * BUF + SA * 8;
    #pragma unroll
    for (int i = 0; i < 4; ++i) {
      const int s = i * 256 + tid;
      *(u32x4*)(dst + s * 8) = __builtin_bit_cast(u32x4, bs[i]);
    }
  };
  auto Compute = [&](int kt) {
    const u16* bufA = lds + (kt & 1) * BUF;
    const u16* bufB = bufA + SA * 8;
    s16x8 av[4], bv[4];
    #pragma unroll
    for (int m = 0; m < 4; ++m) {
      const int r = m * 16 + (l & 15), p = (l >> 4) ^ ((r >> 1) & 3);
      av[m] = *(const s16x8*)(bufA + (r * 4 + p) * 8);   // broadcast across waves
    }
    #pragma unroll
    for (int n = 0; n < 4; ++n) {
      const int cc = w * 64 + n * 16 + (l & 15), p = (l >> 4) ^ ((cc >> 1) & 3);
      bv[n] = *(const s16x8*)(bufB + (cc * 4 + p) * 8);
    }
    #pragma unroll
    for (int m = 0; m < 4; ++m)
      #pragma unroll
      for (int n = 0; n < 4; ++n)
        acc[m][n] = __builtin_amdgcn_mfma_f32_16x16x32_bf16(av[m], bv[n], acc[m][n], 0, 0, 0);
  };

  // prologue: st DMA + first two steps' reg loads; drain own VMEM, then BARRIER
  // (cross-wave DMA visibility), then first write.
  for (int q = tid; q < KH / 4; q += 256) {
    if (q < KH / 8) async16(scE + q * 8, stS + q * 8);
    else            async16(shE + (q - KH / 8) * 8, stT + (q - KH / 8) * 8);
  }
  Aissue(0, h0); Bissue(0, b0r);
  Aissue(1, h1); Bissue(1, b1r);
  asm volatile("s_waitcnt vmcnt(0)" ::: "memory");
  __builtin_amdgcn_s_barrier();              // st visible to ALL waves
  Awrite(0, h0); Bwrite(0, b0r);
  asm volatile("s_waitcnt lgkmcnt(0)" ::: "memory");
  __builtin_amdgcn_s_barrier();

  // steady: {issue(kt+2); compute(kt); write(kt+1); lgkm0; barrier} x2
  #pragma unroll 1
  for (int kt = 0; kt + 3 < KT; kt += 2) {
    Aissue(kt + 2, h0); Bissue(kt + 2, b0r);
    Compute(kt);
    Awrite(kt + 1, h1); Bwrite(kt + 1, b1r);
    asm volatile("s_waitcnt lgkmcnt(0)" ::: "memory");
    __builtin_amdgcn_s_barrier();
    Aissue(kt + 3, h1); Bissue(kt + 3, b1r);
    Compute(kt + 1);
    Awrite(kt + 2, h0); Bwrite(kt + 2, b0r);
    asm volatile("s_waitcnt lgkmcnt(0)" ::: "memory");
    __builtin_amdgcn_s_barrier();
  }

  // tail: steps KT-2, KT-1
  Compute(KT - 2);
  Awrite(KT - 1, h1); Bwrite(KT - 1, b1r);
  asm volatile("s_waitcnt lgkmcnt(0)" ::: "memory");
  __builtin_amdgcn_s_barrier();
  Compute(KT - 1);

  float* dstF = ks ? partial : outF;
  #pragma unroll
  for (int n = 0; n < 4; ++n) {
    const int colg = w * 64 + n * 16 + (l & 15);
    const float bval = ks ? 0.f : b2[e * O_ + colg];
    #pragma unroll
    for (int m = 0; m < 4; ++m) {
      #pragma unroll
      for (int i = 0; i < 4; ++i) {
        const int rg = bt * BM + m * 16 + (l >> 4) * 4 + i;
        dstF[((size_t)rg * C_ + c) * O_ + colg] = acc[m][n][i] + bval;
      }
    }
  }
}

// ---------------- combine split-K partial ----------------
__global__ void k_combine(float* __restrict__ out, const float* __restrict__ partial) {
  const int gi = blockIdx.x * 256 + threadIdx.x;     // 8 floats each
  const size_t b = (size_t)gi * 2;
  f32x4 a0 = ((const f32x4*)out)[b], a1 = ((const f32x4*)out)[b + 1];
  const f32x4 p0 = ((const f32x4*)partial)[b], p1 = ((const f32x4*)partial)[b + 1];
  #pragma unroll
  for (int j = 0; j < 4; ++j) { a0[j] += p0[j]; a1[j] += p1[j]; }
  ((f32x4*)out)[b] = a0; ((f32x4*)out)[b + 1] = a1;
}

extern "C" void kernel_launch(void* const* d_in, const int* in_sizes, int n_in,
                              void* d_out, int out_size, void* d_ws, size_t ws_size,
                              hipStream_t stream) {
  const float* x     = (const float*)d_in[0];
  const int*   mask  = (const int*)d_in[1];
  const int*   proj  = (const int*)d_in[2];
  const float* W1    = (const float*)d_in[3];
  const float* b1    = (const float*)d_in[4];
  const float* gamma = (const float*)d_in[5];
  const float* beta  = (const float*)d_in[6];
  const float* W2    = (const float*)d_in[7];
  const float* b2    = (const float*)d_in[8];
  float* out = (float*)d_out;

  char* ws = (char*)d_ws;
  size_t off = 0;
  u16* hbuf = (u16*)(ws + off); off += (size_t)B_ * C_ * H_ * 2;   // 128 MB, tiled [c][32][B][128]
  u16* xb   = (u16*)(ws + off); off += (size_t)B_ * C_ * D_ * 2;   // 8 MB
  u16* w1t  = (u16*)(ws + off); off += (size_t)E_ * D_ * H_ * 2;   // 8 MB  [E][H][D]
  float* partial = (float*)xb;   // 16 MB, aliases xb+w1t (both dead after gemm1)
  u16* w2t  = (u16*)(ws + off); off += (size_t)E_ * H_ * O_ * 2;   // 8 MB  [E][O][H]
  float* s1p = (float*)(ws + off); off += (size_t)2 * C_ * H_ * 4; // 2 MB [c*2+bt][H]
  float* s2p = (float*)(ws + off); off += (size_t)2 * C_ * H_ * 4; // 2 MB
  u16* sclB = (u16*)(ws + off); off += (size_t)E_ * H_ * 2;
  u16* shfB = (u16*)(ws + off); off += (size_t)E_ * H_ * 2;
  int* perm = (int*)(ws + off); off += 256;

  k_prep<<<4105, 256, 0, stream>>>(x, xb, W1, w1t, W2, w2t, mask,
                                   out + (size_t)B_ * C_ * O_, proj, perm);

  k_gemm1<<<C_ * 2 * 32, 256, 0, stream>>>(xb, w1t, proj, perm, b1, hbuf, s1p, s2p);

  k_finalize<<<E_ * H_ / 256, 256, 0, stream>>>(s1p, s2p, proj, gamma, beta, sclB, shfB);

  // grid = C * (B/64) * KS = 64*4*2 = 512 blocks
  k_gemm2<<<512, 256, 0, stream>>>(hbuf, w2t, proj, perm, b2, sclB, shfB, out, partial);

  k_combine<<<B_ * C_ * O_ / 8 / 256, 256, 0, stream>>>(out, partial);
}